// Round 17
// baseline (79.969 us; speedup 1.0000x reference)
//
#include <hip/hip_runtime.h>

#define DIM 128
#define BUCK 8           // dst nodes per bucket (MFMA tile uses 8 of 16 rows)
#define PCH 8192         // edges per partition chunk
#define NBMAX 8192       // max buckets (n <= 65536)
#define BAT 128          // threads in fused aggregate (2 waves x 4 nodes)
#define CAPB 256         // fixed csr slots per bucket (avg 128, max ~190; overflow-safe)
#define NTS 512          // setup kernel block size
#define CONV_BLKS 256
#define WPACK_BLKS 8

typedef __attribute__((ext_vector_type(8))) short short8;
typedef __attribute__((ext_vector_type(8))) unsigned short ushort8;
typedef __attribute__((ext_vector_type(4))) float f32x4;
typedef __attribute__((ext_vector_type(2))) float f32x2;

static __device__ __forceinline__ unsigned short f32_to_bf16(float f) {
    union { float f; unsigned int u; } c; c.f = f;
    unsigned int u = c.u;
    u += 0x7FFFu + ((u >> 16) & 1u);   // RNE
    return (unsigned short)(u >> 16);
}

// ONE setup kernel (512 threads), three independent block roles:
//  [0, PBLKS):            chunk-local partition into fixed-capacity bucket regions
//  [PBLKS, +CONV_BLKS):   x f32 -> bf16 table AND fp8(e4m3) gather table
//  [+, +WPACK_BLKS):      weight pack (MFMA B-fragment order) + combined bias
__global__ void __launch_bounds__(NTS)
setup_partition_kernel(const float* __restrict__ x, const int* __restrict__ ei,
                       const float* __restrict__ w_self, const float* __restrict__ b_self,
                       const float* __restrict__ w_neigh, const float* __restrict__ b_neigh,
                       unsigned short* __restrict__ xb, unsigned int* __restrict__ xf8,
                       unsigned short* __restrict__ w_swz,
                       float* __restrict__ bias, int* __restrict__ gcur,
                       int* __restrict__ ovfc, unsigned int* __restrict__ csr,
                       unsigned int* __restrict__ ovf,
                       int n4, int E, int NB, int PBLKS) {
    int b = blockIdx.x, t = threadIdx.x;
    if (b < PBLKS) {
        __shared__ int hist[NBMAX];            // pass 1: counts; pass 2: local cursor
        __shared__ unsigned int bav[NBMAX];    // packed base<<16 | avail
        int cbase = b * PCH;
        int cend = min(E, cbase + PCH);
        for (int i = t; i < NB; i += NTS) hist[i] = 0;
        __syncthreads();
        for (int e = cbase + t; e < cend; e += NTS)
            atomicAdd(&hist[ei[E + e] >> 3], 1);
        __syncthreads();
        for (int bk = t; bk < NB; bk += NTS) {
            int c = hist[bk];
            unsigned int pack = 0;
            if (c) {
                int r = atomicAdd(&gcur[bk], c);
                int base = min(r, CAPB);
                int av = min(c, CAPB - base);
                pack = ((unsigned int)base << 16) | (unsigned int)av;
            }
            bav[bk] = pack;
            hist[bk] = 0;                      // becomes local cursor
        }
        __syncthreads();
        for (int e = cbase + t; e < cend; e += NTS) {
            unsigned int src = (unsigned int)ei[e];
            unsigned int dst = (unsigned int)ei[E + e];
            int bk = (int)(dst >> 3);
            int idx = atomicAdd(&hist[bk], 1);
            unsigned int pk = (dst << 16) | src;
            unsigned int pa = bav[bk];
            int base = (int)(pa >> 16), av = (int)(pa & 0xFFFFu);
            if (idx < av) csr[(size_t)bk * CAPB + base + idx] = pk;
            else ovf[atomicAdd(ovfc, 1)] = pk;   // rare
        }
    } else if (b < PBLKS + CONV_BLKS) {
        for (int g = (b - PBLKS) * NTS + t; g < n4; g += CONV_BLKS * NTS) {
            float4 v = reinterpret_cast<const float4*>(x)[g];
            ushort4 s = make_ushort4(f32_to_bf16(v.x), f32_to_bf16(v.y),
                                     f32_to_bf16(v.z), f32_to_bf16(v.w));
            reinterpret_cast<ushort4*>(xb)[g] = s;
            int p = __builtin_amdgcn_cvt_pk_fp8_f32(v.x, v.y, 0, false);   // bytes 0,1
            p = __builtin_amdgcn_cvt_pk_fp8_f32(v.z, v.w, p, true);        // bytes 2,3
            xf8[g] = (unsigned int)p;
        }
    } else {
        int g = (b - PBLKS - CONV_BLKS) * NTS + t;   // 4096 slots
        if (g < 128) bias[g] = b_self[g] + b_neigh[g];
        if (g >= 64 * 64) return;
        int f = g >> 6, l = g & 63;
        int ks = f >> 3, nf = f & 7;
        int j = nf * 16 + (l & 15);
        int kbase = ks * 32 + ((l >> 4) << 3);
#pragma unroll
        for (int e = 0; e < 8; ++e) {
            int k = kbase + e;
            float v = (k < 128) ? w_self[(size_t)j * 128 + k]
                                : w_neigh[(size_t)j * 128 + (k - 128)];
            w_swz[((size_t)g << 3) + e] = f32_to_bf16(v);
        }
    }
}

// FUSED aggregate + finalize. One block per 8-node bucket, 2 waves (~9.1KB LDS
// -> 16 blocks/CU = 32 waves/CU, the HW cap; grid 6250 keeps every CU full).
// fp8 gather: one dwordx2 x 16 lanes covers a 128B row -> 4 edges/instr,
// 4 quad-loads in flight, node loop unroll 2 (8 loads). 2 shfl_xor reduce,
// mean -> bf16 A-tile rows 0..7 (rows 8..15 zero), 2-wave 16x16 MFMA epilogue
// with C-writes guarded to rows < BUCK.
__global__ void __launch_bounds__(BAT)
fused_aggregate_kernel(const unsigned short* __restrict__ xb,
                       const unsigned int* __restrict__ xf8,
                       const int* __restrict__ gcur,
                       const int* __restrict__ ovfc,
                       const unsigned int* __restrict__ csr,
                       const unsigned int* __restrict__ ovf,
                       const unsigned short* __restrict__ w_swz,
                       const float* __restrict__ bias,
                       float* __restrict__ out, int n) {
    __shared__ unsigned short srt[CAPB];       // sorted src ids (0.5KB)
    __shared__ unsigned short xm[16][264];     // [x(128) | mean(128)] bf16 (8.4KB)
    __shared__ int bin[BUCK];
    __shared__ int boff_s[BUCK + 1];
    __shared__ int cur[BUCK];

    int tid = threadIdx.x, wid = tid >> 6, lane = tid & 63;
    int grp = lane >> 4, j = lane & 15;     // 4 groups of 16 lanes
    int b0 = blockIdx.x;
    int bsize = min(gcur[b0], CAPB);
    int ovfn = ovfc[0];
    const unsigned int* my = csr + (size_t)b0 * CAPB;
    int gbase = b0 * BUCK;
    const uint2* x8 = reinterpret_cast<const uint2*>(xf8);   // 16 uint2 per fp8 row

    // Stage x rows 0..7 into A-tile (bf16, coalesced); rows 8..15 + mean area zero.
    for (int fi = tid; fi < 16 * 32; fi += BAT) {
        int row = fi >> 5, c = fi & 31;
        ushort8 s = (ushort8)0;
        if (row < BUCK && c < 16) {
            int grow = gbase + row;
            if (grow < n) s = reinterpret_cast<const ushort8*>(xb + (size_t)grow * DIM)[c];
        }
        *reinterpret_cast<ushort8*>(&xm[row][c * 8]) = s;
    }

    // ---- counting sort by local dst (8 bins) ----
    for (int i = tid; i < BUCK; i += BAT) bin[i] = 0;
    __syncthreads();
    for (int i = tid; i < bsize; i += BAT)
        atomicAdd(&bin[(my[i] >> 16) & 7], 1);
    __syncthreads();
    if (wid == 0) {   // lanes 0..7 scan 8 bins
        int v = (lane < BUCK) ? bin[lane] : 0;
        int s = v;
#pragma unroll
        for (int d = 1; d < BUCK; d <<= 1) {
            int u = __shfl_up(s, d, 64);
            if (lane >= d) s += u;
        }
        if (lane < BUCK) {
            boff_s[lane] = s - v;
            cur[lane] = s - v;
            if (lane == BUCK - 1) boff_s[BUCK] = s;
        }
    }
    __syncthreads();
    for (int i = tid; i < bsize; i += BAT) {
        unsigned int p = my[i];
        int d = (p >> 16) & 7;
        srt[atomicAdd(&cur[d], 1)] = (unsigned short)(p & 0xFFFFu);
    }
    __syncthreads();

    // ---- per-node gather (fp8), 4 edges/instr, unroll 2 over nodes ----
#pragma unroll 2
    for (int i = 0; i < 4; ++i) {
        int nd = wid * 4 + i;
        int s = boff_s[nd], epd = boff_s[nd + 1];
        f32x2 c0 = {0.f, 0.f}, c1 = {0.f, 0.f}, c2 = {0.f, 0.f}, c3 = {0.f, 0.f};
        for (int e = s; e < epd; e += 16) {
            uint2 v[4];
#pragma unroll
            for (int q = 0; q < 4; ++q) {
                int eidx = e + q * 4 + grp;
                bool ok = eidx < epd;
                uint2 tv = x8[(size_t)srt[ok ? eidx : s] * 16 + j];
                v[q] = ok ? tv : make_uint2(0u, 0u);
            }
#pragma unroll
            for (int q = 0; q < 4; ++q) {
                c0 += __builtin_amdgcn_cvt_pk_f32_fp8(v[q].x, false);
                c1 += __builtin_amdgcn_cvt_pk_f32_fp8(v[q].x, true);
                c2 += __builtin_amdgcn_cvt_pk_f32_fp8(v[q].y, false);
                c3 += __builtin_amdgcn_cvt_pk_f32_fp8(v[q].y, true);
            }
        }
        int deg = epd - s;
        // Overflow edges (normally ovfn == 0).
        for (int o = 0; o < ovfn; ++o) {
            unsigned int p = ovf[o];
            if ((int)(p >> 16) == gbase + nd) {
                uint2 tv = x8[(size_t)(p & 0xFFFFu) * 16 + j];
                c0 += __builtin_amdgcn_cvt_pk_f32_fp8(tv.x, false);
                c1 += __builtin_amdgcn_cvt_pk_f32_fp8(tv.x, true);
                c2 += __builtin_amdgcn_cvt_pk_f32_fp8(tv.y, false);
                c3 += __builtin_amdgcn_cvt_pk_f32_fp8(tv.y, true);
                ++deg;
            }
        }
        // cross-group reduce: sum the 4 lane-groups (same 8-col set each).
        float t[8] = {c0.x, c0.y, c1.x, c1.y, c2.x, c2.y, c3.x, c3.y};
#pragma unroll
        for (int k = 0; k < 8; ++k) {
            t[k] += __shfl_xor(t[k], 16);
            t[k] += __shfl_xor(t[k], 32);
        }
        float inv = deg > 0 ? 1.0f / (float)deg : 0.f;
        if (grp == 0) {
            ushort8 m = (ushort8)0;
#pragma unroll
            for (int k = 0; k < 8; ++k) m[k] = f32_to_bf16(t[k] * inv);
            *reinterpret_cast<ushort8*>(&xm[nd][128 + j * 8]) = m;
        }
    }
    __syncthreads();

    // ---- MFMA epilogue: 2 waves, wave = 16 rows x 64 cols (8 rows valid) ----
    int ch = wid;
    int arow = lane & 15;
    int koff = (lane >> 4) << 3;

    f32x4 acc[4];
#pragma unroll
    for (int nf = 0; nf < 4; ++nf) acc[nf] = (f32x4){0.f, 0.f, 0.f, 0.f};

#pragma unroll
    for (int ks = 0; ks < 8; ++ks) {
        short8 a = *reinterpret_cast<const short8*>(&xm[arow][ks * 32 + koff]);
#pragma unroll
        for (int nf = 0; nf < 4; ++nf) {
            int f = ks * 8 + ch * 4 + nf;
            short8 b = *reinterpret_cast<const short8*>(w_swz + (((size_t)f * 64 + lane) << 3));
            acc[nf] = __builtin_amdgcn_mfma_f32_16x16x32_bf16(a, b, acc[nf], 0, 0, 0);
        }
    }

    int crow0 = (lane >> 4) << 2;
    if (crow0 < BUCK) {
#pragma unroll
        for (int nf = 0; nf < 4; ++nf) {
            int col = (ch * 4 + nf) * 16 + (lane & 15);
            float bs = bias[col];
#pragma unroll
            for (int r = 0; r < 4; ++r) {
                int grow = gbase + crow0 + r;
                if (grow < n) out[(size_t)grow * DIM + col] = acc[nf][r] + bs;
            }
        }
    }
}

extern "C" void kernel_launch(void* const* d_in, const int* in_sizes, int n_in,
                              void* d_out, int out_size, void* d_ws, size_t ws_size,
                              hipStream_t stream) {
    const float* x       = (const float*)d_in[0];
    const int*   ei      = (const int*)d_in[1];
    const float* w_self  = (const float*)d_in[2];
    const float* b_self  = (const float*)d_in[3];
    const float* w_neigh = (const float*)d_in[4];
    const float* b_neigh = (const float*)d_in[5];
    float* out = (float*)d_out;

    int n = in_sizes[0] / DIM;
    int E = in_sizes[1] / 2;
    int NB = (n + BUCK - 1) / BUCK;   // 6250 for n=50000; requires NB <= NBMAX

    // ws: gcur[NBMAX] | ovfc[4] | csr uint[NB*CAPB] (~6.4MB) | ovf uint[E] (~3.2MB) |
    //     (align16) w_swz bf16[32768] | bias f32[128] | x_bf bf16[n*128] (~12.8MB) |
    //     x_fp8 uint[n*32] (~6.4MB)
    int* gcur = (int*)d_ws;
    int* ovfc = gcur + NBMAX;
    unsigned int* csr = (unsigned int*)(ovfc + 4);
    unsigned int* ovf = csr + (size_t)NB * CAPB;
    unsigned short* w_swz = (unsigned short*)(((uintptr_t)(ovf + E) + 15) & ~(uintptr_t)15);
    float* bias = (float*)(w_swz + 64 * 64 * 8);
    unsigned short* x_bf = (unsigned short*)(bias + 128);
    unsigned int* x_fp8 = (unsigned int*)(x_bf + (size_t)n * DIM);

    hipMemsetAsync(gcur, 0, (NBMAX + 4) * sizeof(int), stream);

    int n4 = n * DIM / 4;
    int PBLKS = (E + PCH - 1) / PCH;   // 98
    setup_partition_kernel<<<PBLKS + CONV_BLKS + WPACK_BLKS, NTS, 0, stream>>>(
        x, ei, w_self, b_self, w_neigh, b_neigh, x_bf, x_fp8, w_swz, bias,
        gcur, ovfc, csr, ovf, n4, E, NB, PBLKS);

    fused_aggregate_kernel<<<NB, BAT, 0, stream>>>(x_bf, x_fp8, gcur, ovfc, csr, ovf,
                                                   w_swz, bias, out, n);
}

// Round 18
// 61.924 us; speedup vs baseline: 1.2914x; 1.2914x over previous
//
#include <hip/hip_runtime.h>

#define DIM 128
#define BUCK 16          // dst nodes per bucket == MFMA tile rows
#define PCH 4096         // edges per partition chunk
#define NBMAX 4096       // max buckets (n <= 65536)
#define BAT 128          // threads in fused aggregate (2 waves x 8 nodes)
#define CAPB 512         // fixed csr slots per bucket (avg 256, max ~360; overflow-safe)
#define NTS 512          // setup kernel block size
#define CONV_BLKS 256
#define WPACK_BLKS 8

typedef __attribute__((ext_vector_type(8))) short short8;
typedef __attribute__((ext_vector_type(8))) unsigned short ushort8;
typedef __attribute__((ext_vector_type(4))) float f32x4;
typedef __attribute__((ext_vector_type(2))) float f32x2;

static __device__ __forceinline__ unsigned short f32_to_bf16(float f) {
    union { float f; unsigned int u; } c; c.f = f;
    unsigned int u = c.u;
    u += 0x7FFFu + ((u >> 16) & 1u);   // RNE
    return (unsigned short)(u >> 16);
}

// ONE setup kernel (512 threads), three independent block roles:
//  [0, PBLKS):            chunk-local partition into fixed-capacity bucket regions
//  [PBLKS, +CONV_BLKS):   x f32 -> bf16 table AND fp8(e4m3) gather table
//  [+, +WPACK_BLKS):      weight pack (MFMA B-fragment order) + combined bias
__global__ void __launch_bounds__(NTS)
setup_partition_kernel(const float* __restrict__ x, const int* __restrict__ ei,
                       const float* __restrict__ w_self, const float* __restrict__ b_self,
                       const float* __restrict__ w_neigh, const float* __restrict__ b_neigh,
                       unsigned short* __restrict__ xb, unsigned int* __restrict__ xf8,
                       unsigned short* __restrict__ w_swz,
                       float* __restrict__ bias, int* __restrict__ gcur,
                       int* __restrict__ ovfc, unsigned int* __restrict__ csr,
                       unsigned int* __restrict__ ovf,
                       int n4, int E, int NB, int PBLKS) {
    int b = blockIdx.x, t = threadIdx.x;
    if (b < PBLKS) {
        __shared__ int hist[NBMAX];            // pass 1: counts; pass 2: local cursor
        __shared__ unsigned int bav[NBMAX];    // packed base<<16 | avail
        int cbase = b * PCH;
        int cend = min(E, cbase + PCH);
        for (int i = t; i < NB; i += NTS) hist[i] = 0;
        __syncthreads();
        for (int e = cbase + t; e < cend; e += NTS)
            atomicAdd(&hist[ei[E + e] >> 4], 1);
        __syncthreads();
        for (int bk = t; bk < NB; bk += NTS) {
            int c = hist[bk];
            unsigned int pack = 0;
            if (c) {
                int r = atomicAdd(&gcur[bk], c);
                int base = min(r, CAPB);
                int av = min(c, CAPB - base);
                pack = ((unsigned int)base << 16) | (unsigned int)av;
            }
            bav[bk] = pack;
            hist[bk] = 0;                      // becomes local cursor
        }
        __syncthreads();
        for (int e = cbase + t; e < cend; e += NTS) {
            unsigned int src = (unsigned int)ei[e];
            unsigned int dst = (unsigned int)ei[E + e];
            int bk = (int)(dst >> 4);
            int idx = atomicAdd(&hist[bk], 1);
            unsigned int pk = (dst << 16) | src;
            unsigned int pa = bav[bk];
            int base = (int)(pa >> 16), av = (int)(pa & 0xFFFFu);
            if (idx < av) csr[(size_t)bk * CAPB + base + idx] = pk;
            else ovf[atomicAdd(ovfc, 1)] = pk;   // rare
        }
    } else if (b < PBLKS + CONV_BLKS) {
        for (int g = (b - PBLKS) * NTS + t; g < n4; g += CONV_BLKS * NTS) {
            float4 v = reinterpret_cast<const float4*>(x)[g];
            ushort4 s = make_ushort4(f32_to_bf16(v.x), f32_to_bf16(v.y),
                                     f32_to_bf16(v.z), f32_to_bf16(v.w));
            reinterpret_cast<ushort4*>(xb)[g] = s;
            int p = __builtin_amdgcn_cvt_pk_fp8_f32(v.x, v.y, 0, false);   // bytes 0,1
            p = __builtin_amdgcn_cvt_pk_fp8_f32(v.z, v.w, p, true);        // bytes 2,3
            xf8[g] = (unsigned int)p;
        }
    } else {
        int g = (b - PBLKS - CONV_BLKS) * NTS + t;   // 4096 slots
        if (g < 128) bias[g] = b_self[g] + b_neigh[g];
        if (g >= 64 * 64) return;
        int f = g >> 6, l = g & 63;
        int ks = f >> 3, nf = f & 7;
        int j = nf * 16 + (l & 15);
        int kbase = ks * 32 + ((l >> 4) << 3);
#pragma unroll
        for (int e = 0; e < 8; ++e) {
            int k = kbase + e;
            float v = (k < 128) ? w_self[(size_t)j * 128 + k]
                                : w_neigh[(size_t)j * 128 + (k - 128)];
            w_swz[((size_t)g << 3) + e] = f32_to_bf16(v);
        }
    }
}

// FUSED aggregate + finalize. One block per 16-node bucket, 2 waves (~10KB LDS).
// fp8 gather: one dwordx2 x 16 lanes covers a 128B row -> 4 edges/instr,
// 4 quad-loads (16 edges) in flight. 2 shfl_xor reduce, mean -> bf16 A-tile,
// 2-wave MFMA epilogue (wave = 16 rows x 64 cols).
__global__ void __launch_bounds__(BAT)
fused_aggregate_kernel(const unsigned short* __restrict__ xb,
                       const unsigned int* __restrict__ xf8,
                       const int* __restrict__ gcur,
                       const int* __restrict__ ovfc,
                       const unsigned int* __restrict__ csr,
                       const unsigned int* __restrict__ ovf,
                       const unsigned short* __restrict__ w_swz,
                       const float* __restrict__ bias,
                       float* __restrict__ out, int n) {
    __shared__ unsigned short srt[CAPB];       // sorted src ids (1KB)
    __shared__ unsigned short xm[BUCK][264];   // [x(128) | mean(128)] bf16 (8.25KB)
    __shared__ int bin[BUCK];
    __shared__ int boff_s[BUCK + 1];
    __shared__ int cur[BUCK];

    int tid = threadIdx.x, wid = tid >> 6, lane = tid & 63;
    int grp = lane >> 4, j = lane & 15;     // 4 groups of 16 lanes
    int b0 = blockIdx.x;
    int bsize = min(gcur[b0], CAPB);
    int ovfn = ovfc[0];
    const unsigned int* my = csr + (size_t)b0 * CAPB;
    int gbase = b0 * BUCK;
    const uint2* x8 = reinterpret_cast<const uint2*>(xf8);   // 16 uint2 per fp8 row

    // Stage x rows into A-tile x-part (coalesced, bf16).
    for (int fi = tid; fi < BUCK * 16; fi += BAT) {
        int row = fi >> 4, c = fi & 15;
        int grow = gbase + row;
        ushort8 s = (ushort8)0;
        if (grow < n) s = reinterpret_cast<const ushort8*>(xb + (size_t)grow * DIM)[c];
        *reinterpret_cast<ushort8*>(&xm[row][c * 8]) = s;
    }

    // ---- counting sort by local dst (16 bins) ----
    for (int i = tid; i < BUCK; i += BAT) bin[i] = 0;
    __syncthreads();
    for (int i = tid; i < bsize; i += BAT)
        atomicAdd(&bin[(my[i] >> 16) & 15], 1);
    __syncthreads();
    if (wid == 0) {   // lanes 0..15 scan 16 bins
        int v = (lane < BUCK) ? bin[lane] : 0;
        int s = v;
#pragma unroll
        for (int d = 1; d < BUCK; d <<= 1) {
            int u = __shfl_up(s, d, 64);
            if (lane >= d) s += u;
        }
        if (lane < BUCK) {
            boff_s[lane] = s - v;
            cur[lane] = s - v;
            if (lane == BUCK - 1) boff_s[BUCK] = s;
        }
    }
    __syncthreads();
    for (int i = tid; i < bsize; i += BAT) {
        unsigned int p = my[i];
        int d = (p >> 16) & 15;
        srt[atomicAdd(&cur[d], 1)] = (unsigned short)(p & 0xFFFFu);
    }
    __syncthreads();

    // ---- per-node gather (fp8), 4 edges/instr, 16 edges in flight ----
#pragma unroll 2
    for (int i = 0; i < 8; ++i) {
        int nd = wid * 8 + i;
        int s = boff_s[nd], epd = boff_s[nd + 1];
        f32x2 c0 = {0.f, 0.f}, c1 = {0.f, 0.f}, c2 = {0.f, 0.f}, c3 = {0.f, 0.f};
        for (int e = s; e < epd; e += 16) {
            uint2 v[4];
#pragma unroll
            for (int q = 0; q < 4; ++q) {
                int eidx = e + q * 4 + grp;
                bool ok = eidx < epd;
                uint2 tv = x8[(size_t)srt[ok ? eidx : s] * 16 + j];
                v[q] = ok ? tv : make_uint2(0u, 0u);
            }
#pragma unroll
            for (int q = 0; q < 4; ++q) {
                c0 += __builtin_amdgcn_cvt_pk_f32_fp8(v[q].x, false);
                c1 += __builtin_amdgcn_cvt_pk_f32_fp8(v[q].x, true);
                c2 += __builtin_amdgcn_cvt_pk_f32_fp8(v[q].y, false);
                c3 += __builtin_amdgcn_cvt_pk_f32_fp8(v[q].y, true);
            }
        }
        int deg = epd - s;
        // Overflow edges (normally ovfn == 0).
        for (int o = 0; o < ovfn; ++o) {
            unsigned int p = ovf[o];
            if ((int)(p >> 16) == gbase + nd) {
                uint2 tv = x8[(size_t)(p & 0xFFFFu) * 16 + j];
                c0 += __builtin_amdgcn_cvt_pk_f32_fp8(tv.x, false);
                c1 += __builtin_amdgcn_cvt_pk_f32_fp8(tv.x, true);
                c2 += __builtin_amdgcn_cvt_pk_f32_fp8(tv.y, false);
                c3 += __builtin_amdgcn_cvt_pk_f32_fp8(tv.y, true);
                ++deg;
            }
        }
        // cross-group reduce: sum the 4 lane-groups (same 8-col set each).
        float t[8] = {c0.x, c0.y, c1.x, c1.y, c2.x, c2.y, c3.x, c3.y};
#pragma unroll
        for (int k = 0; k < 8; ++k) {
            t[k] += __shfl_xor(t[k], 16);
            t[k] += __shfl_xor(t[k], 32);
        }
        float inv = deg > 0 ? 1.0f / (float)deg : 0.f;
        if (grp == 0) {
            ushort8 m = (ushort8)0;
#pragma unroll
            for (int k = 0; k < 8; ++k) m[k] = f32_to_bf16(t[k] * inv);
            *reinterpret_cast<ushort8*>(&xm[nd][128 + j * 8]) = m;
        }
    }
    __syncthreads();

    // ---- MFMA epilogue: 2 waves, wave = 16 rows x 64 cols ----
    int ch = wid;
    int arow = lane & 15;
    int koff = (lane >> 4) << 3;

    f32x4 acc[4];
#pragma unroll
    for (int nf = 0; nf < 4; ++nf) acc[nf] = (f32x4){0.f, 0.f, 0.f, 0.f};

#pragma unroll
    for (int ks = 0; ks < 8; ++ks) {
        short8 a = *reinterpret_cast<const short8*>(&xm[arow][ks * 32 + koff]);
#pragma unroll
        for (int nf = 0; nf < 4; ++nf) {
            int f = ks * 8 + ch * 4 + nf;
            short8 b = *reinterpret_cast<const short8*>(w_swz + (((size_t)f * 64 + lane) << 3));
            acc[nf] = __builtin_amdgcn_mfma_f32_16x16x32_bf16(a, b, acc[nf], 0, 0, 0);
        }
    }

    int crow0 = (lane >> 4) << 2;
#pragma unroll
    for (int nf = 0; nf < 4; ++nf) {
        int col = (ch * 4 + nf) * 16 + (lane & 15);
        float bs = bias[col];
#pragma unroll
        for (int r = 0; r < 4; ++r) {
            int grow = gbase + crow0 + r;
            if (grow < n) out[(size_t)grow * DIM + col] = acc[nf][r] + bs;
        }
    }
}

extern "C" void kernel_launch(void* const* d_in, const int* in_sizes, int n_in,
                              void* d_out, int out_size, void* d_ws, size_t ws_size,
                              hipStream_t stream) {
    const float* x       = (const float*)d_in[0];
    const int*   ei      = (const int*)d_in[1];
    const float* w_self  = (const float*)d_in[2];
    const float* b_self  = (const float*)d_in[3];
    const float* w_neigh = (const float*)d_in[4];
    const float* b_neigh = (const float*)d_in[5];
    float* out = (float*)d_out;

    int n = in_sizes[0] / DIM;
    int E = in_sizes[1] / 2;
    int NB = (n + BUCK - 1) / BUCK;   // 3125 for n=50000; requires NB <= NBMAX

    // ws: gcur[NBMAX] | ovfc[4] | csr uint[NB*CAPB] (~6.4MB) | ovf uint[E] (~3.2MB) |
    //     (align16) w_swz bf16[32768] | bias f32[128] | x_bf bf16[n*128] (~12.8MB) |
    //     x_fp8 uint[n*32] (~6.4MB)
    int* gcur = (int*)d_ws;
    int* ovfc = gcur + NBMAX;
    unsigned int* csr = (unsigned int*)(ovfc + 4);
    unsigned int* ovf = csr + (size_t)NB * CAPB;
    unsigned short* w_swz = (unsigned short*)(((uintptr_t)(ovf + E) + 15) & ~(uintptr_t)15);
    float* bias = (float*)(w_swz + 64 * 64 * 8);
    unsigned short* x_bf = (unsigned short*)(bias + 128);
    unsigned int* x_fp8 = (unsigned int*)(x_bf + (size_t)n * DIM);

    hipMemsetAsync(gcur, 0, (NBMAX + 4) * sizeof(int), stream);

    int n4 = n * DIM / 4;
    int PBLKS = (E + PCH - 1) / PCH;   // 196
    setup_partition_kernel<<<PBLKS + CONV_BLKS + WPACK_BLKS, NTS, 0, stream>>>(
        x, ei, w_self, b_self, w_neigh, b_neigh, x_bf, x_fp8, w_swz, bias,
        gcur, ovfc, csr, ovf, n4, E, NB, PBLKS);

    fused_aggregate_kernel<<<NB, BAT, 0, stream>>>(x_bf, x_fp8, gcur, ovfc, csr, ovf,
                                                   w_swz, bias, out, n);
}